// Round 3
// baseline (3048.438 us; speedup 1.0000x reference)
//
#include <hip/hip_runtime.h>
#include <hip/hip_fp16.h>
#include <math.h>

#define TT 1600
#define BB 48
#define VV 1000
#define LL 128
#define TILE 32                       // timesteps per DP LDS tile
#define NTILES 50                     // 50 * 32 = 1600
#define NDP BB                        // 48 DP blocks, blockIdx 0..47 (dispatched first)
#define GROWS 4                       // (t,b) rows per gather block
#define NGATHER (TT * BB / GROWS)     // 19200 gather blocks
#define BLKPERTILE (TILE * BB / GROWS)// 384 gather blocks complete one t-tile
#define LN1024 6.93147180559945309f   // emissions pre-scaled by 2^10 -> fp16 normal range

// DPP helper: pure-VALU cross-lane, no LDS counter traffic.
#define DPPF(x, ctrl) __int_as_float(__builtin_amdgcn_update_dpp( \
    0, __float_as_int(x), (ctrl), 0xf, 0xf, true))

typedef const __attribute__((address_space(1))) unsigned int* gldlds_src_t;
typedef __attribute__((address_space(3))) unsigned int*       gldlds_dst_t;
typedef unsigned long long u64;

// Shared-memory union: gather branch uses rb (16000 B), DP branch uses dp
// (16384 + 256 = 16640 B). Union keeps the block footprint at 16.6 KB so
// gather occupancy is unaffected by fusion.
struct DPShared {
  unsigned int sbuf[2][TILE * 64];    // 2 x 8192 B fp16 label tiles
  float        pbt[2][TILE];          // 2 x 128 B blank-prob tiles
};
union FusedSM {
  float    rb[4000];                  // 4 rows x 1000 floats (gather staging)
  DPShared dp;
};

// ---------------------------------------------------------------------------
// Fused kernel.
//  blockIdx <  48 : DP consumer for batch b = blockIdx (3 stage waves spin on
//                   per-tile counters, pull em via agent-scope atomic loads).
//  blockIdx >= 48 : gather worker: stage 4 lp rows -> LDS -> gather+exp ->
//                   agent-scope atomic stores of fp16 em, then release-add
//                   the tile counter.
// Dependency is one-way (gather never waits) -> deadlock-free in any
// dispatch order; worst case degenerates to the old serial behavior.
// ---------------------------------------------------------------------------
__global__ __launch_bounds__(256) void ctc_fused(
    const float* __restrict__ lp,
    const int* __restrict__ targets,
    const int* __restrict__ input_lengths,
    __half* __restrict__ emL,
    float* __restrict__ emB,
    unsigned int* __restrict__ counters,
    float* __restrict__ partial)
{
  __shared__ FusedSM sm;
  const int tid  = threadIdx.x;
  const int wv   = tid >> 6;
  const int lane = tid & 63;

  if (blockIdx.x >= NDP) {
    // ---------------- gather branch ----------------
    const size_t row0 = (size_t)(blockIdx.x - NDP) * GROWS;
    const float4* src = (const float4*)(lp + row0 * VV);   // 1000 f4, contiguous
#pragma unroll
    for (int i = 0; i < 4; i++) {
      int idx = tid + (i << 8);
      if (idx < 1000)
        __builtin_amdgcn_global_load_lds(
            (gldlds_src_t)(src + idx),
            (gldlds_dst_t)(sm.rb + ((size_t)((i << 8) + (wv << 6)) << 2)),
            16, 0, 0);
    }
    __syncthreads();                           // drains vmcnt

    const int t  = (int)(row0 / BB);
    const int b  = (int)(row0 % BB) + wv;      // one row per wave
    const int2 g = ((const int2*)(targets + b * LL))[lane];
    const float* row = sm.rb + wv * 1000;
    float e0 = __expf(row[g.x] + LN1024);
    float e1 = __expf(row[g.y] + LN1024);
    __half2 h = __floats2half2_rn(e0, e1);
    __hip_atomic_store((unsigned int*)emL + (size_t)(t * BB + b) * 64 + lane,
                       *reinterpret_cast<unsigned int*>(&h),
                       __ATOMIC_RELAXED, __HIP_MEMORY_SCOPE_AGENT);
    if (lane == 0)
      __hip_atomic_store((unsigned int*)emB + (size_t)b * TT + t,
                         __float_as_uint(__expf(row[0] + LN1024)),
                         __ATOMIC_RELAXED, __HIP_MEMORY_SCOPE_AGENT);
    __threadfence();                           // order stores before the flag
    __syncthreads();
    if (tid == 0)
      __hip_atomic_fetch_add(&counters[t >> 5], 1u,
                             __ATOMIC_RELEASE, __HIP_MEMORY_SCOPE_AGENT);
    return;
  }

  // ---------------- DP branch ----------------
  const int b  = blockIdx.x;
  const int NS = input_lengths[b] - 1;         // steps t = 1..NS

  // ----- consumer lane-local constants -----
  float skip1 = 0.f, skip3 = 0.f, m63 = 0.f, sel1648 = 0.f, sel32 = 0.f;
  if (wv == 0) {
    const int* __restrict__ tg = targets + b * LL;
    const int c0  = tg[2 * lane];
    const int c1  = tg[2 * lane + 1];
    const int cm1 = (lane > 0) ? tg[2 * lane - 1] : c0;
    skip1   = (lane > 0 && c0 != cm1) ? 1.0f : 0.0f;
    skip3   = (c1 != c0) ? 1.0f : 0.0f;
    m63     = (lane == 63) ? 1.0f : 0.0f;
    sel1648 = (lane == 16 || lane == 48) ? 1.0f : 0.0f;
    sel32   = (lane == 32) ? 1.0f : 0.0f;
  }

  float a0 = 0.f, a1 = 0.f, a2 = 0.f, a3 = 0.f, a4 = 0.f;
  int esum = 0;
  float sc_p = 1.0f;                           // pending (deferred) scale
  int   se_p = 0;
  float  pb_r[8];
  float2 ev_r[8];

  // Acquire-spin until gather published tile KN (counter hits 384).
#define WAITTILE(KN) do {                                            \
    while (__hip_atomic_load(&counters[KN], __ATOMIC_ACQUIRE,        \
                             __HIP_MEMORY_SCOPE_AGENT) < BLKPERTILE) \
      __builtin_amdgcn_s_sleep(2);                                   \
  } while (0)

  // 3 producer waves pull the 32-row tile (1024 u64) + 32 blank floats via
  // agent-scope atomic loads (coherent across XCDs), then ds_write to LDS.
#define STAGE(KN) do {                                               \
    const u64* srcL_ = (const u64*)emL                               \
        + ((size_t)(KN) * TILE * BB + b) * 32;                       \
    u64* dstL_ = (u64*)(sm.dp.sbuf[(KN) & 1]);                       \
    for (int i_ = ((wv - 1) << 6) + lane; i_ < TILE * 32; i_ += 192) { \
      u64 v_ = __hip_atomic_load(                                    \
          srcL_ + (size_t)(i_ >> 5) * (BB * 32) + (i_ & 31),         \
          __ATOMIC_RELAXED, __HIP_MEMORY_SCOPE_AGENT);               \
      dstL_[i_] = v_;                                                \
    }                                                                \
    if (wv == 1 && lane < 16) {                                      \
      u64 pv_ = __hip_atomic_load(                                   \
          (const u64*)(emB + (size_t)b * TT + (KN) * TILE) + lane,   \
          __ATOMIC_RELAXED, __HIP_MEMORY_SCOPE_AGENT);               \
      ((u64*)sm.dp.pbt[(KN) & 1])[lane] = pv_;                       \
    }                                                                \
  } while (0)

  // alpha_old[4l-1]: DPP row_shr:1 (row-edge lanes -> 0), patch lanes 16/48
  // from row_bcast15 and lane 32 from row_bcast31.
#define STEP(PB, EV) do {                                            \
    float am1 = DPPF(a3, 0x111);                                     \
    float h15 = DPPF(a3, 0x142);                                     \
    float h31 = DPPF(a3, 0x143);                                     \
    am1 = fmaf(sel1648, h15, am1);                                   \
    am1 = fmaf(sel32,   h31, am1);                                   \
    float s0 = a0 + am1;                                             \
    float s1 = fmaf(skip1, am1, a0 + a1);                            \
    float s2 = a1 + a2;                                              \
    float s3 = fmaf(skip3, a1, a2 + a3);                             \
    float s4 = fmaf(a3, m63, a4);                                    \
    a0 = s0 * (PB); a1 = s1 * (EV).x; a2 = s2 * (PB);                \
    a3 = s3 * (EV).y; a4 = s4 * (PB);                                \
  } while (0)

  // Apply previous group's scale, then start this group's max-reduce; the
  // result is consumed only one group later (latency hidden).
#define RESCALE_DEFERRED() do {                                      \
    a0 *= sc_p; a1 *= sc_p; a2 *= sc_p; a3 *= sc_p; a4 *= sc_p;      \
    esum -= se_p;                                                    \
    float mx = fmaxf(fmaxf(fmaxf(a0, a1), fmaxf(a2, a3)), a4);       \
    mx = fmaxf(mx, DPPF(mx, 0x111));                                 \
    mx = fmaxf(mx, DPPF(mx, 0x112));                                 \
    mx = fmaxf(mx, DPPF(mx, 0x114));                                 \
    mx = fmaxf(mx, DPPF(mx, 0x118));                                 \
    mx = fmaxf(mx, DPPF(mx, 0x142));                                 \
    mx = fmaxf(mx, DPPF(mx, 0x143));     /* lane63 = wave max */     \
    int eb = (__builtin_amdgcn_readlane(__float_as_int(mx), 63) >> 23) & 0xFF; \
    int se = 133 - eb;                   /* aim max at ~2^6 */       \
    se = se < -126 ? -126 : (se > 127 ? 127 : se);                   \
    sc_p = __uint_as_float((unsigned)(se + 127) << 23);              \
    se_p = se;                                                       \
  } while (0)

  if (wv) { WAITTILE(0); STAGE(0); }
  __syncthreads();

  for (int k = 0; k < NTILES; k++) {
    if (wv) {
      if (k + 1 < NTILES) { WAITTILE(k + 1); STAGE(k + 1); }
    } else {
      const unsigned int* tb  = sm.dp.sbuf[k & 1];
      const float*        pbb = sm.dp.pbt[k & 1];
      if (k == 0 && lane == 0) {               // t=0 init
        a0 = pbb[0];
        unsigned int u0 = tb[0];
        a1 = __half22float2(*reinterpret_cast<const __half2*>(&u0)).x;
      }
      int tbeg = (k == 0) ? 1 : k * TILE;
      int tend = k * TILE + TILE - 1;
      if (tend > NS) tend = NS;
      int n = tend - tbeg + 1;
      if (n > 0) {
        const unsigned int* lb0 = tb + (tbeg - k * TILE) * 64 + lane;
        const float*        pb0 = pbb + (tbeg - k * TILE);
#define LOADSLOT(D, TF) do {                                         \
    pb_r[D] = pb0[TF];                       /* uniform -> bcast */  \
    unsigned int u_ = lb0[(TF) * 64];        /* 2-way alias: free */ \
    ev_r[D] = __half22float2(*reinterpret_cast<const __half2*>(&u_)); \
  } while (0)
#pragma unroll
        for (int d = 0; d < 8; d++) { if (d < n) LOADSLOT(d, d); }
        int i = 0;
        while (i + 8 <= n) {
#pragma unroll
          for (int d = 0; d < 8; d++) {
            STEP(pb_r[d], ev_r[d]);
            int tf = i + 8 + d;
            if (tf < n) LOADSLOT(d, tf);
          }
          RESCALE_DEFERRED();
          i += 8;
        }
#pragma unroll
        for (int d = 0; d < 7; d++) {
          if (i + d < n) STEP(pb_r[d], ev_r[d]);
        }
#undef LOADSLOT
      }
    }
    __syncthreads();
  }

  if (wv == 0 && lane == 63) {
    a3 *= sc_p; a4 *= sc_p; esum -= se_p;      // flush pending scale
    // alpha[255] = a3, alpha[256] = a4; stored = true * 1024^(NS+1) * 2^-esum
    float tot = __logf(a3 + a4)
              + ((float)esum - 10.0f * (float)(NS + 1)) * 0.69314718055994530942f;
    partial[b] = tot;                          // plain store; kernel boundary
  }                                            // makes it visible to reduce
#undef STEP
#undef RESCALE_DEFERRED
#undef STAGE
#undef WAITTILE
}

// ---------------------------------------------------------------------------
// 48-lane final reduce: out = -sum_b partial[b]. Runs after the fused kernel
// (stream order => visibility), overwrites out (no memset needed).
// ---------------------------------------------------------------------------
__global__ __launch_bounds__(64) void ctc_reduce(
    const float* __restrict__ partial, float* __restrict__ out)
{
  const int lane = threadIdx.x & 63;
  float v = (lane < BB) ? partial[lane] : 0.0f;
#pragma unroll
  for (int o = 32; o; o >>= 1) v += __shfl_xor(v, o);
  if (lane == 0) *out = -v;
}

// ---------------------------------------------------------------------------
extern "C" void kernel_launch(void* const* d_in, const int* in_sizes, int n_in,
                              void* d_out, int out_size, void* d_ws, size_t ws_size,
                              hipStream_t stream) {
  const float* lp            = (const float*)d_in[0];
  const int*   targets       = (const int*)d_in[1];
  const int*   input_lengths = (const int*)d_in[2];

  unsigned int* counters = (unsigned int*)d_ws;              // 50 x 4 B
  float*  partial = (float*)((char*)d_ws + 256);             // 48 floats
  float*  emB     = (float*)((char*)d_ws + 4096);            // 307,200 B
  __half* emL     = (__half*)((char*)d_ws + 4096 + 307200);  // 19.66 MB
  float*  out     = (float*)d_out;

  hipMemsetAsync(counters, 0, 256, stream);    // zero tile counters (ws poisoned)
  ctc_fused<<<NDP + NGATHER, 256, 0, stream>>>(
      lp, targets, input_lengths, emL, emB, counters, partial);
  ctc_reduce<<<1, 64, 0, stream>>>(partial, out);
}